// Round 6
// baseline (949.355 us; speedup 1.0000x reference)
//
#include <hip/hip_runtime.h>
#include <hip/hip_bf16.h>

#define N_NODES 50000
#define N_EDGES 800000
#define DIM 128
#define NHEAD 4
#define GEMM_BLOCKS 782    // ceil(N/64)
#define HBLOCKS 313        // ceil(E / 2560) edge-chunk blocks for hist/scatter
#define EPB 2560           // edges per hist/scatter block (10 x 256)
#define NBUCK 196          // src buckets = node>>8 (50000/256); same for dst
#define NBUCK2 392         // src + dst buckets
#define NODE_PAD 50432     // 196*256 = 50176 rounded up

typedef __bf16 bf16x8 __attribute__((ext_vector_type(8)));
typedef float f32x4 __attribute__((ext_vector_type(4)));

struct WPtrs { const float* w[5]; };

// ---------------- weight prep: fp32 W[k][col] -> bf16 Wt[col][k] ----------------
__global__ __launch_bounds__(256) void prep_weights(WPtrs P, __bf16* __restrict__ Wt)
{
  __shared__ __bf16 tileT[16][136];
  const int mat = blockIdx.x >> 3, sl = blockIdx.x & 7;
  const float* W = P.w[mat];
  const int col0 = sl * 16;
  const int t = threadIdx.x;
  #pragma unroll
  for (int i = 0; i < 8; ++i) {
    int id = t + i * 256;              // 2048 = 128 k x 16 c
    int k = id >> 4, c = id & 15;
    tileT[c][k] = (__bf16)W[k * 128 + col0 + c];
  }
  __syncthreads();
  int c = t >> 4, kb = t & 15;
  bf16x8 v = *(const bf16x8*)&tileT[c][kb * 8];
  *(bf16x8*)&Wt[(size_t)mat * 16384 + (size_t)(col0 + c) * 128 + kb * 8] = v;
}

// ---------------- GEMM building blocks ----------------
// aLDS[64][136], wLDS[64][136] (64-col half of W^T at a time -> 35KB LDS ->
// 4 blocks/CU). R12: occupancy is the binding resource for these latency-bound
// GEMMs — 128-wide wLDS (3 blocks/CU) regressed fat1 ~15% (R3). Keep 4/CU.

__device__ __forceinline__ void stage_Wt_half(const __bf16* __restrict__ Wt,
    int half, __bf16 (*wLDS)[136])
{
  const int t = threadIdx.x;
  const __bf16* base = Wt + (size_t)half * 64 * 128;
  #pragma unroll
  for (int i = 0; i < 4; ++i) {
    int id = t + i * 256;              // 1024 chunks: col = id>>4 (0..63), kb = id&15
    int col = id >> 4, kb = id & 15;
    bf16x8 v = ((const bf16x8*)(base + (size_t)col * 128))[kb];
    *(bf16x8*)&wLDS[col][kb * 8] = v;
  }
}

__device__ __forceinline__ void stage_A_f32(const float* __restrict__ A, int row0,
    int nrows, __bf16 (*aLDS)[136])
{
  const int t = threadIdx.x;
  #pragma unroll
  for (int i = 0; i < 4; ++i) {
    int id = t + i * 256;
    int r = id >> 4, cb = id & 15;
    int gr = row0 + r;
    float4 v0 = make_float4(0.f, 0.f, 0.f, 0.f), v1 = v0;
    if (gr < nrows) {
      const float4* row = (const float4*)(A + (size_t)gr * DIM);
      v0 = row[cb * 2];
      v1 = row[cb * 2 + 1];
    }
    bf16x8 o;
    o[0] = (__bf16)v0.x; o[1] = (__bf16)v0.y; o[2] = (__bf16)v0.z; o[3] = (__bf16)v0.w;
    o[4] = (__bf16)v1.x; o[5] = (__bf16)v1.y; o[6] = (__bf16)v1.z; o[7] = (__bf16)v1.w;
    *(bf16x8*)&aLDS[r][cb * 8] = o;
  }
}

__device__ __forceinline__ void stage_A_bf16(const __bf16* __restrict__ A, int row0,
    int nrows, __bf16 (*aLDS)[136])
{
  const int t = threadIdx.x;
  #pragma unroll
  for (int i = 0; i < 4; ++i) {
    int id = t + i * 256;
    int r = id >> 4, cb = id & 15;
    int gr = row0 + r;
    bf16x8 v = {};
    if (gr < nrows) v = ((const bf16x8*)(A + (size_t)gr * DIM))[cb];
    *(bf16x8*)&aLDS[r][cb * 8] = v;
  }
}

// acc index j covers col = (j>>2)*64 + (j&3)*16 + m.  C/D layout (verified m89):
// col = lane&15 (+tile col), row = (lane>>4)*4 + reg.
__device__ __forceinline__ void mfma_half(const __bf16 (*aLDS)[136],
    const __bf16 (*wLDS)[136], int half, f32x4 acc[8])
{
  const int lane = threadIdx.x & 63, wave = threadIdx.x >> 6;
  const int m = lane & 15, q = lane >> 4;
  #pragma unroll
  for (int kt = 0; kt < 4; ++kt) {
    bf16x8 a = *(const bf16x8*)&aLDS[wave * 16 + m][kt * 32 + q * 8];
    #pragma unroll
    for (int ct = 0; ct < 4; ++ct) {
      bf16x8 b = *(const bf16x8*)&wLDS[ct * 16 + m][kt * 32 + q * 8];
      acc[half * 4 + ct] =
          __builtin_amdgcn_mfma_f32_16x16x32_bf16(a, b, acc[half * 4 + ct], 0, 0, 0);
    }
  }
}

template <typename OutT>
__device__ __forceinline__ void store_tile(f32x4 acc[8],
    const float* __restrict__ bias, float scale, OutT* __restrict__ C,
    int row0, int nrows)
{
  const int lane = threadIdx.x & 63, wave = threadIdx.x >> 6;
  const int m = lane & 15, q = lane >> 4;
  #pragma unroll
  for (int j = 0; j < 8; ++j) {
    int col = (j >> 2) * 64 + (j & 3) * 16 + m;
    float bv = bias[col];
    #pragma unroll
    for (int r = 0; r < 4; ++r) {
      int row = row0 + wave * 16 + q * 4 + r;
      if (row < nrows) C[(size_t)row * DIM + col] = (OutT)((acc[j][r] + bv) * scale);
    }
  }
}

// one full 128-col GEMM pass over the staged A tile (two W halves)
__device__ __forceinline__ void gemm_pass(const __bf16 (*aLDS)[136],
    __bf16 (*wLDS)[136], const __bf16* __restrict__ Wt, f32x4 acc[8])
{
  #pragma unroll
  for (int i = 0; i < 8; ++i) acc[i] = (f32x4){0.f, 0.f, 0.f, 0.f};
  stage_Wt_half(Wt, 0, wLDS);
  __syncthreads();
  mfma_half(aLDS, wLDS, 0, acc);
  __syncthreads();
  stage_Wt_half(Wt, 1, wLDS);
  __syncthreads();
  mfma_half(aLDS, wLDS, 1, acc);
}

// ---------------- fat1: edge histogram || {K,M,Q} gemm (mat-split) ----------------
// R13: the K/M/Q GEMMs are latency-bound — 3 independent block sets (3x overlap),
// mat-minor ordering so the 3 readers of an x row dispatch adjacently (L3 share).
// Hist half: per-block LDS histograms over 392 buckets, zero global atomics (R11).
__global__ __launch_bounds__(256) void fat1(const int* __restrict__ ei,
    int* __restrict__ hist,
    const __bf16* __restrict__ Wt, const float* __restrict__ x,
    const float* __restrict__ bk, const float* __restrict__ bm,
    const float* __restrict__ bq,
    __bf16* __restrict__ Kn, __bf16* __restrict__ Mn, __bf16* __restrict__ Qn)
{
  __shared__ __bf16 aLDS[64][136];
  __shared__ __bf16 wLDS[64][136];
  const int b = blockIdx.x, t = threadIdx.x;

  if (b < HBLOCKS) {
    int* h = (int*)&aLDS[0][0];        // 392 ints in a corner of aLDS
    for (int i = t; i < NBUCK2; i += 256) h[i] = 0;
    __syncthreads();
    #pragma unroll
    for (int i = 0; i < 10; ++i) {
      int e = b * EPB + i * 256 + t;
      if (e < N_EDGES) {
        int s = ei[e], d = ei[N_EDGES + e];
        atomicAdd(&h[s >> 8], 1);
        atomicAdd(&h[NBUCK + (d >> 8)], 1);
      }
    }
    __syncthreads();
    for (int i = t; i < NBUCK2; i += 256) hist[b * NBUCK2 + i] = h[i];
  } else {
    const int gb = b - HBLOCKS;
    const int mat = gb % 3;            // mat-minor: 3 mats of one row adjacent
    const int row0 = (gb / 3) * 64;
    const float* bias = (mat == 0) ? bk : (mat == 1) ? bm : bq;
    __bf16* out = (mat == 0) ? Kn : (mat == 1) ? Mn : Qn;
    const float scale = (mat == 2) ? 0.17677669529663689f : 1.0f;
    f32x4 acc[8];
    stage_A_f32(x, row0, N_NODES, aLDS);
    gemm_pass(aLDS, wLDS, Wt + (size_t)mat * 16384, acc);
    store_tile<__bf16>(acc, bias, scale, out, row0, N_NODES);
  }
}

// ---------------- per-bucket scan over blocks: bbase[blk][b], tot[b] ----------------
__global__ __launch_bounds__(64) void bucket_scan(const int* __restrict__ hist,
    int* __restrict__ bbase, int* __restrict__ tot)
{
  const int b = blockIdx.x, l = threadIdx.x;   // one wave per bucket
  int run = 0;
  for (int c = 0; c < 5; ++c) {                // ceil(313/64)
    int idx = c * 64 + l;
    int v = (idx < HBLOCKS) ? hist[idx * NBUCK2 + b] : 0;
    int orig = v;
    #pragma unroll
    for (int o = 1; o < 64; o <<= 1) {
      int n = __shfl_up(v, o);
      if (l >= o) v += n;
    }
    if (idx < HBLOCKS) bbase[idx * NBUCK2 + b] = run + v - orig;  // exclusive
    run += __shfl(v, 63);
  }
  if (l == 0) tot[b] = run;
}

// ---------------- exclusive scan of bucket totals (src and dst separately) ----------------
__global__ __launch_bounds__(256) void bucket_starts(const int* __restrict__ tot,
    int* __restrict__ bstart)
{
  __shared__ int s[256];
  const int t = threadIdx.x;
  int v = (t < NBUCK) ? tot[t] : 0;
  s[t] = v; __syncthreads();
  for (int o = 1; o < 256; o <<= 1) {
    int x = (t >= o) ? s[t - o] : 0; __syncthreads();
    s[t] += x; __syncthreads();
  }
  if (t < NBUCK) bstart[t] = s[t] - v;
  __syncthreads();
  v = (t < NBUCK) ? tot[NBUCK + t] : 0;
  s[t] = v; __syncthreads();
  for (int o = 1; o < 256; o <<= 1) {
    int x = (t >= o) ? s[t - o] : 0; __syncthreads();
    s[t] += x; __syncthreads();
  }
  if (t < NBUCK) bstart[NBUCK + t] = s[t] - v;
}

// ---------------- scatter edges into per-bucket segments ----------------
// R14: slotD (the edge's dst-bucket slot) is known AT SCATTER TIME — carried in
// bucketedS's payload; wexp is indexed by slotD so the two rank sides are
// independent. bucketedD carries only pk (4B), its index IS slotD.
__global__ __launch_bounds__(256) void edge_scatter(const int* __restrict__ ei,
    const int* __restrict__ bbase, const int* __restrict__ bstart,
    int2* __restrict__ bucketedS, int* __restrict__ bucketedD)
{
  __shared__ int base[NBUCK2];
  __shared__ int cur[NBUCK2];
  const int b = blockIdx.x, t = threadIdx.x;
  for (int i = t; i < NBUCK2; i += 256) {
    base[i] = bstart[i] + bbase[b * NBUCK2 + i];
    cur[i] = 0;
  }
  __syncthreads();
  #pragma unroll
  for (int i = 0; i < 10; ++i) {
    int e = b * EPB + i * 256 + t;
    if (e < N_EDGES) {
      int s = ei[e], d = ei[N_EDGES + e];
      int pk = s | (d << 16);
      int bs = s >> 8, bd = NBUCK + (d >> 8);
      int lo = atomicAdd(&cur[bs], 1);
      int ld = atomicAdd(&cur[bd], 1);
      int slotD = base[bd] + ld;             // global dst-side slot in [0,E)
      bucketedS[base[bs] + lo] = make_int2(pk, slotD);
      bucketedD[slotD] = pk;
    }
  }
}

// ---------------- src-side rank: elistS = (dst, slotD) + starts/deg ----------------
__global__ __launch_bounds__(256) void bucket_rank_src(const int2* __restrict__ bucketedS,
    const int* __restrict__ bstart, const int* __restrict__ tot,
    int2* __restrict__ elistS, int* __restrict__ starts, int* __restrict__ deg)
{
  __shared__ int c1[256], ns[256], c2[256];
  const int b = blockIdx.x, t = threadIdx.x;
  const int seg0 = bstart[b];
  const int cnt = tot[b];
  const int2* ent = bucketedS + seg0;

  c1[t] = 0; c2[t] = 0;
  __syncthreads();
  for (int i = t; i < cnt; i += 256)
    atomicAdd(&c1[(int)((unsigned)ent[i].x & 0xFFFFu) - (b << 8)], 1);
  __syncthreads();
  ns[t] = c1[t]; __syncthreads();
  for (int o = 1; o < 256; o <<= 1) {
    int x = (t >= o) ? ns[t - o] : 0; __syncthreads();
    ns[t] += x; __syncthreads();
  }
  {
    int node = (b << 8) + t;
    starts[node] = seg0 + ns[t] - c1[t];
    deg[node] = c1[t];
  }
  __syncthreads();
  ns[t] -= c1[t];
  __syncthreads();
  for (int i = t; i < cnt; i += 256) {
    int2 en = ent[i];
    unsigned pk = (unsigned)en.x;
    int ln = (int)(pk & 0xFFFFu) - (b << 8);
    int r = atomicAdd(&c2[ln], 1);
    elistS[seg0 + ns[ln] + r] = make_int2((int)(pk >> 16), en.y);
  }
}

// ---------------- dst-side rank: sort bucket edges by (dst-half, src-bucket) ------
// R15: the aggregation's Mn gather becomes cache-hot by CONSTRUCTION — edges of
// each dst-bucket sorted by (dl>>7)*196 + (src>>8), so agg_dst streams through
// 64KB src windows. elistA = (src | dl<<16, slotD). aoff/acnt give each
// half-bucket's edge range. 392 bins -> 512-padded ping-pong LDS scan.
__global__ __launch_bounds__(256) void bucket_rank_dstA(const int* __restrict__ bucketedD,
    const int* __restrict__ bstart, const int* __restrict__ tot,
    int2* __restrict__ elistA, int* __restrict__ aoff, int* __restrict__ acnt)
{
  __shared__ int c1[NBUCK2], c2[NBUCK2];
  __shared__ int sA[512], sB[512];
  const int b = blockIdx.x, t = threadIdx.x;
  const int seg0 = bstart[NBUCK + b];
  const int cnt = tot[NBUCK + b];
  const int* ent = bucketedD + seg0;

  for (int i = t; i < NBUCK2; i += 256) { c1[i] = 0; c2[i] = 0; }
  __syncthreads();
  for (int i = t; i < cnt; i += 256) {
    unsigned pk = (unsigned)ent[i];
    int dl = (int)(pk >> 16) - (b << 8);
    int sb = (int)(pk & 0xFFFFu) >> 8;
    atomicAdd(&c1[(dl >> 7) * NBUCK + sb], 1);
  }
  __syncthreads();
  sA[t] = (t < NBUCK2) ? c1[t] : 0;
  sA[t + 256] = (t + 256 < NBUCK2) ? c1[t + 256] : 0;
  __syncthreads();
  int* pin = sA; int* pout = sB;
  for (int o = 1; o < 512; o <<= 1) {
    pout[t] = pin[t] + ((t >= o) ? pin[t - o] : 0);
    int i2 = t + 256;
    pout[i2] = pin[i2] + ((i2 >= o) ? pin[i2 - o] : 0);
    __syncthreads();
    int* tmp = pin; pin = pout; pout = tmp;
  }
  // pin = inclusive scan over 392 bins (padded)
  int ns0 = pin[t] - c1[t];
  int ns1 = (t + 256 < NBUCK2) ? (pin[t + 256] - c1[t + 256]) : 0;
  __syncthreads();
  c1[t] = ns0;                           // c1 becomes exclusive bin offsets
  if (t + 256 < NBUCK2) c1[t + 256] = ns1;
  if (t == 0) {
    int h0 = pin[NBUCK - 1];             // edges in half 0
    aoff[b * 2] = 0;      acnt[b * 2] = h0;
    aoff[b * 2 + 1] = h0; acnt[b * 2 + 1] = cnt - h0;
  }
  __syncthreads();
  for (int i = t; i < cnt; i += 256) {
    unsigned pk = (unsigned)ent[i];
    int src = (int)(pk & 0xFFFFu);
    int dl = (int)(pk >> 16) - (b << 8);
    int key = (dl >> 7) * NBUCK + (src >> 8);
    int r = atomicAdd(&c2[key], 1);
    elistA[seg0 + c1[key] + r] = make_int2(src | (dl << 16), seg0 + i);
  }
}

// ---------------- pass 1: scores+exp, one wave per SRC node ----------------
// wexp stores RAW exp at the edge's dst-side slot (slotD from elistS payload);
// per-src factor deg/ssum stored to factor[n][h]. No max-shift: |score| < ~1.
__global__ __launch_bounds__(256) void src_scores(const int* __restrict__ starts,
    const int* __restrict__ degS, const int2* __restrict__ elistS,
    const __bf16* __restrict__ Qn, const __bf16* __restrict__ Kn,
    float* __restrict__ wexp, float* __restrict__ factor)
{
  const int wave = threadIdx.x >> 6, l = threadIdx.x & 63;
  const int n = blockIdx.x * 4 + wave;
  const int g = l >> 4, il = l & 15;
  const int h = il >> 2;
  const int beg = starts[n], end = beg + degS[n];
  if (beg == end) return;   // factor never read for edge-less src

  bf16x8 q8 = ((const bf16x8*)(Qn + (size_t)n * DIM))[il];
  float wsum = 0.f;

  for (int p0 = beg; p0 < end; p0 += 16) {
    int pp[4]; int2 en[4];
    #pragma unroll
    for (int u = 0; u < 4; ++u) {
      pp[u] = p0 + u * 4 + g;
      en[u] = elistS[min(pp[u], end - 1)];
    }
    bf16x8 kk[4];
    #pragma unroll
    for (int u = 0; u < 4; ++u)
      kk[u] = ((const bf16x8*)(Kn + (size_t)en[u].x * DIM))[il];
    #pragma unroll
    for (int u = 0; u < 4; ++u) {
      float pr = 0.f;
      #pragma unroll
      for (int j = 0; j < 8; ++j) pr += (float)q8[j] * (float)kk[u][j];
      pr += __shfl_xor(pr, 1);
      pr += __shfl_xor(pr, 2);
      float w = (pp[u] < end) ? __expf(pr) : 0.f;
      wsum += w;
      if ((pp[u] < end) && (il & 3) == 0) wexp[(size_t)en[u].y * NHEAD + h] = w;
    }
  }
  wsum += __shfl_xor(wsum, 16);
  wsum += __shfl_xor(wsum, 32);
  if (g == 0 && (il & 3) == 0)
    factor[(size_t)n * NHEAD + h] = (float)(end - beg) / wsum;
}

// ---------------- pass 2: LDS-accumulated aggregation, edges (half,src-bucket)-sorted --
// Block bb: dst-bucket b=bb>>1, half=bb&1 (128 dst rows, 64KB fp32 LDS acc,
// 2 blocks/CU). Edges streamed sequentially; Mn reads walk 64KB src windows
// (L1/L2-hot); wexp/factor reads bucket-local. ds_add_f32 accumulate; +4 pad
// floats/row to spread banks.
__global__ __launch_bounds__(256) void agg_dst(const int2* __restrict__ elistA,
    const int* __restrict__ bstart, const int* __restrict__ aoff,
    const int* __restrict__ acnt,
    const __bf16* __restrict__ Mn, const float* __restrict__ wexp,
    const float* __restrict__ factor, __bf16* __restrict__ agg)
{
  __shared__ float aggL[128][132];
  const int bb = blockIdx.x, t = threadIdx.x;
  const int b = bb >> 1, half = bb & 1;
  const int seg0 = bstart[NBUCK + b];
  const int e0 = seg0 + aoff[bb], e1 = e0 + acnt[bb];

  for (int i = t; i < 128 * 132; i += 256) ((float*)aggL)[i] = 0.f;
  __syncthreads();

  const int g16 = t >> 4;              // 16 edge-groups across the block
  const int il = t & 15;               // 16 lanes/edge, 8 dims each
  const int h = il >> 2;

  for (int p0 = e0; p0 < e1; p0 += 64) {
    int pp[4]; int2 ea[4];
    #pragma unroll
    for (int u = 0; u < 4; ++u) {
      pp[u] = p0 + u * 16 + g16;
      ea[u] = elistA[min(pp[u], e1 - 1)];
    }
    float ww[4]; bf16x8 mm[4];
    #pragma unroll
    for (int u = 0; u < 4; ++u) {
      int src = ea[u].x & 0xFFFF;
      ww[u] = wexp[(size_t)ea[u].y * NHEAD + h] * factor[src * NHEAD + h];
      mm[u] = ((const bf16x8*)(Mn + (size_t)src * DIM))[il];
    }
    #pragma unroll
    for (int u = 0; u < 4; ++u) {
      if (pp[u] < e1) {
        int row = ((ea[u].x >> 16) & 0xFF) - half * 128;
        float* dstp = &aggL[row][il * 8];
        #pragma unroll
        for (int j = 0; j < 8; ++j)
          atomicAdd(&dstp[j], (float)mm[u][j] * ww[u]);
      }
    }
  }
  __syncthreads();

  for (int i = t; i < 128 * 16; i += 256) {
    int r = i >> 4, cb = i & 15;
    int node = (b << 8) + half * 128 + r;
    if (node < N_NODES) {
      bf16x8 o;
      #pragma unroll
      for (int j = 0; j < 8; ++j) o[j] = (__bf16)aggL[r][cb * 8 + j];
      *(bf16x8*)(agg + (size_t)node * DIM + cb * 8) = o;
    }
  }
}

// ---------------- gemm1: h1 = agg@W1+b1 (bf16 out) + fused column stats ----------------
__global__ __launch_bounds__(256) void gemm_stats(const __bf16* __restrict__ A,
    const __bf16* __restrict__ Wt, const float* __restrict__ bias,
    __bf16* __restrict__ C, float* __restrict__ colsum, float* __restrict__ colsq)
{
  __shared__ __bf16 aLDS[64][136];
  __shared__ __bf16 wLDS[64][136];
  __shared__ float csum[128], csq[128];
  const int t = threadIdx.x;
  const int row0 = blockIdx.x * 64;

  stage_A_bf16(A, row0, N_NODES, aLDS);
  if (t < 128) { csum[t] = 0.f; csq[t] = 0.f; }
  f32x4 acc[8];
  gemm_pass(aLDS, wLDS, Wt, acc);

  const int lane = t & 63, wave = t >> 6;
  const int m = lane & 15, q = lane >> 4;
  #pragma unroll
  for (int j = 0; j < 8; ++j) {
    int col = (j >> 2) * 64 + (j & 3) * 16 + m;
    float bv = bias[col];
    float s = 0.f, s2 = 0.f;
    #pragma unroll
    for (int r = 0; r < 4; ++r) {
      int row = row0 + wave * 16 + q * 4 + r;
      float hv = acc[j][r] + bv;
      if (row < N_NODES) {
        C[(size_t)row * DIM + col] = (__bf16)hv;
        s += hv; s2 += hv * hv;
      }
    }
    s  += __shfl_xor(s, 16);  s  += __shfl_xor(s, 32);
    s2 += __shfl_xor(s2, 16); s2 += __shfl_xor(s2, 32);
    if (q == 0) {
      atomicAdd(&csum[col], s);
      atomicAdd(&csq[col], s2);
    }
  }
  __syncthreads();
  if (t < 128) {
    atomicAdd(&colsum[t], csum[t]);
    atomicAdd(&colsq[t], csq[t]);
  }
}

// ---------------- gemm2: out = relu(BN(h1))@W2+b2, BN folded in ----------------
__global__ __launch_bounds__(256) void gemm_bn(const __bf16* __restrict__ A,
    const __bf16* __restrict__ Wt, const float* __restrict__ bias,
    float* __restrict__ C, const float* __restrict__ colsum,
    const float* __restrict__ colsq, const float* __restrict__ gamma,
    const float* __restrict__ beta)
{
  __shared__ __bf16 aLDS[64][136];
  __shared__ __bf16 wLDS[64][136];
  __shared__ float sA[128], sB[128];
  const int t = threadIdx.x;
  const int row0 = blockIdx.x * 64;

  if (t < 128) {
    float mean = colsum[t] * (1.0f / N_NODES);
    float var = colsq[t] * (1.0f / N_NODES) - mean * mean;  // biased (torch BN)
    float inv = rsqrtf(var + 1e-5f);
    float a = gamma[t] * inv;
    sA[t] = a;
    sB[t] = beta[t] - mean * a;
  }
  __syncthreads();

  {
    const int cb = t & 15;
    float sa[8], sb[8];
    #pragma unroll
    for (int j = 0; j < 8; ++j) { sa[j] = sA[cb * 8 + j]; sb[j] = sB[cb * 8 + j]; }
    #pragma unroll
    for (int i = 0; i < 4; ++i) {
      int id = t + i * 256;
      int r = id >> 4;
      int gr = row0 + r;
      bf16x8 v = {};
      if (gr < N_NODES) v = ((const bf16x8*)(A + (size_t)gr * DIM))[cb];
      bf16x8 o;
      #pragma unroll
      for (int j = 0; j < 8; ++j)
        o[j] = (__bf16)fmaxf((float)v[j] * sa[j] + sb[j], 0.f);
      *(bf16x8*)&aLDS[r][cb * 8] = o;
    }
  }
  f32x4 acc[8];
  gemm_pass(aLDS, wLDS, Wt, acc);
  store_tile<float>(acc, bias, 1.0f, C, row0, N_NODES);
}

extern "C" void kernel_launch(void* const* d_in, const int* in_sizes, int n_in,
                              void* d_out, int out_size, void* d_ws, size_t ws_size,
                              hipStream_t stream) {
  const float* x     = (const float*)d_in[0];
  const int*   ei    = (const int*)d_in[1];
  const float* Wk    = (const float*)d_in[2];
  const float* bk    = (const float*)d_in[3];
  const float* Wm    = (const float*)d_in[4];
  const float* bm    = (const float*)d_in[5];
  const float* Wq    = (const float*)d_in[6];
  const float* bq    = (const float*)d_in[7];
  const float* W1    = (const float*)d_in[8];
  const float* b1    = (const float*)d_in[9];
  const float* gamma = (const float*)d_in[10];
  const float* beta  = (const float*)d_in[11];
  const float* W2    = (const float*)d_in[12];
  const float* b2    = (const float*)d_in[13];

  float* ws = (float*)d_ws;
  const size_t ND  = (size_t)N_NODES * DIM;      // 6,400,000
  const size_t NDh = ND / 2;                     // floats per bf16 ND array
  const size_t EH  = (size_t)N_EDGES * NHEAD;    // 3,200,000

  __bf16* Kn   = (__bf16*)ws;                    // ND bf16
  __bf16* Mn   = (__bf16*)(ws + NDh);            // ND bf16 (unscaled)
  __bf16* Qn   = (__bf16*)(ws + 2 * NDh);        // ND bf16
  __bf16* agg  = (__bf16*)(ws + 3 * NDh);        // ND bf16
  __bf16* h1   = (__bf16*)(ws + 4 * NDh);        // ND bf16
  float*  wexp = ws + 5 * NDh;                   // EH fp32 (raw exp, by slotD)
  // bucketed arrays alias wexp: dead before src_scores writes wexp
  int2*   bucketedS = (int2*)wexp;               // E int2 (pk, slotD)  6.4MB
  int*    bucketedD = (int*)(bucketedS + N_EDGES); // E int (pk)  +3.2MB <= 12.8MB
  int2*   elistS = (int2*)(wexp + EH);           // E int2 (dst, slotD)
  int2*   elistA = elistS + N_EDGES;             // E int2 (src|dl<<16, slotD)
  int*    hist   = (int*)(elistA + N_EDGES);     // HBLOCKS * 392
  int*    bbase  = hist + HBLOCKS * NBUCK2;      // HBLOCKS * 392
  int*    tot    = bbase + HBLOCKS * NBUCK2;     // 392
  int*    bstart = tot + NBUCK2;                 // 392
  int*    aoff   = bstart + NBUCK2;              // 392
  int*    acnt   = aoff + NBUCK2;                // 392
  int*    starts = acnt + NBUCK2;                // NODE_PAD
  int*    deg    = starts + NODE_PAD;            // NODE_PAD
  float*  factor = (float*)(deg + NODE_PAD);     // NHEAD * N
  float*  colsum = factor + (size_t)NHEAD * N_NODES;  // 128
  float*  colsq  = colsum + 128;                 // 128
  __bf16* Wt     = (__bf16*)(colsq + 128);       // 5*16384 bf16
  float*  outp   = (float*)d_out;

  // zero: colsum/colsq only (everything else fully written by kernels)
  hipMemsetAsync(colsum, 0, 256 * sizeof(float), stream);

  const int node_blocks = N_NODES / 4;           // 12500

  WPtrs wp; wp.w[0] = Wk; wp.w[1] = Wm; wp.w[2] = Wq; wp.w[3] = W1; wp.w[4] = W2;
  prep_weights<<<40, 256, 0, stream>>>(wp, Wt);

  fat1<<<HBLOCKS + 3 * GEMM_BLOCKS, 256, 0, stream>>>(
      ei, hist, Wt, x, bk, bm, bq, Kn, Mn, Qn);

  bucket_scan<<<NBUCK2, 64, 0, stream>>>(hist, bbase, tot);
  bucket_starts<<<1, 256, 0, stream>>>(tot, bstart);
  edge_scatter<<<HBLOCKS, 256, 0, stream>>>(ei, bbase, bstart, bucketedS, bucketedD);
  bucket_rank_src<<<NBUCK, 256, 0, stream>>>(bucketedS, bstart, tot,
                                             elistS, starts, deg);
  bucket_rank_dstA<<<NBUCK, 256, 0, stream>>>(bucketedD, bstart, tot,
                                              elistA, aoff, acnt);

  src_scores<<<node_blocks, 256, 0, stream>>>(starts, deg, elistS, Qn, Kn,
                                              wexp, factor);

  agg_dst<<<2 * NBUCK, 256, 0, stream>>>(elistA, bstart, aoff, acnt,
                                         Mn, wexp, factor, agg);

  gemm_stats<<<GEMM_BLOCKS, 256, 0, stream>>>(agg, Wt + 3 * 16384, b1, h1,
                                              colsum, colsq);
  gemm_bn<<<GEMM_BLOCKS, 256, 0, stream>>>(h1, Wt + 4 * 16384, b2, outp,
                                           colsum, colsq, gamma, beta);
}

// Round 7
// 290.772 us; speedup vs baseline: 3.2649x; 3.2649x over previous
//
#include <hip/hip_runtime.h>
#include <hip/hip_bf16.h>

#define N_NODES 50000
#define N_EDGES 800000
#define DIM 128
#define NHEAD 4
#define GEMM_BLOCKS 782    // ceil(N/64)
#define HBLOCKS 313        // ceil(E / 2560) edge-chunk blocks for hist/scatter
#define EPB 2560           // edges per hist/scatter block (10 x 256)
#define NBUCK 196          // src buckets = node>>8 (50000/256); same for dst
#define NBUCK2 392         // src + dst buckets
#define NODE_PAD 50432     // 196*256 = 50176 rounded up

typedef __bf16 bf16x8 __attribute__((ext_vector_type(8)));
typedef float f32x4 __attribute__((ext_vector_type(4)));

struct WPtrs { const float* w[5]; };

// ---------------- weight prep: fp32 W[k][col] -> bf16 Wt[col][k] ----------------
__global__ __launch_bounds__(256) void prep_weights(WPtrs P, __bf16* __restrict__ Wt)
{
  __shared__ __bf16 tileT[16][136];
  const int mat = blockIdx.x >> 3, sl = blockIdx.x & 7;
  const float* W = P.w[mat];
  const int col0 = sl * 16;
  const int t = threadIdx.x;
  #pragma unroll
  for (int i = 0; i < 8; ++i) {
    int id = t + i * 256;              // 2048 = 128 k x 16 c
    int k = id >> 4, c = id & 15;
    tileT[c][k] = (__bf16)W[k * 128 + col0 + c];
  }
  __syncthreads();
  int c = t >> 4, kb = t & 15;
  bf16x8 v = *(const bf16x8*)&tileT[c][kb * 8];
  *(bf16x8*)&Wt[(size_t)mat * 16384 + (size_t)(col0 + c) * 128 + kb * 8] = v;
}

// ---------------- GEMM building blocks ----------------
// aLDS[64][136], wLDS[64][136] (64-col half of W^T at a time -> 35KB LDS ->
// 4 blocks/CU). R12: occupancy is the binding resource for these latency-bound
// GEMMs — 128-wide wLDS (3 blocks/CU) regressed fat1 ~15% (R3). Keep 4/CU.

__device__ __forceinline__ void stage_Wt_half(const __bf16* __restrict__ Wt,
    int half, __bf16 (*wLDS)[136])
{
  const int t = threadIdx.x;
  const __bf16* base = Wt + (size_t)half * 64 * 128;
  #pragma unroll
  for (int i = 0; i < 4; ++i) {
    int id = t + i * 256;              // 1024 chunks: col = id>>4 (0..63), kb = id&15
    int col = id >> 4, kb = id & 15;
    bf16x8 v = ((const bf16x8*)(base + (size_t)col * 128))[kb];
    *(bf16x8*)&wLDS[col][kb * 8] = v;
  }
}

__device__ __forceinline__ void stage_A_f32(const float* __restrict__ A, int row0,
    int nrows, __bf16 (*aLDS)[136])
{
  const int t = threadIdx.x;
  #pragma unroll
  for (int i = 0; i < 4; ++i) {
    int id = t + i * 256;
    int r = id >> 4, cb = id & 15;
    int gr = row0 + r;
    float4 v0 = make_float4(0.f, 0.f, 0.f, 0.f), v1 = v0;
    if (gr < nrows) {
      const float4* row = (const float4*)(A + (size_t)gr * DIM);
      v0 = row[cb * 2];
      v1 = row[cb * 2 + 1];
    }
    bf16x8 o;
    o[0] = (__bf16)v0.x; o[1] = (__bf16)v0.y; o[2] = (__bf16)v0.z; o[3] = (__bf16)v0.w;
    o[4] = (__bf16)v1.x; o[5] = (__bf16)v1.y; o[6] = (__bf16)v1.z; o[7] = (__bf16)v1.w;
    *(bf16x8*)&aLDS[r][cb * 8] = o;
  }
}

__device__ __forceinline__ void stage_A_bf16(const __bf16* __restrict__ A, int row0,
    int nrows, __bf16 (*aLDS)[136])
{
  const int t = threadIdx.x;
  #pragma unroll
  for (int i = 0; i < 4; ++i) {
    int id = t + i * 256;
    int r = id >> 4, cb = id & 15;
    int gr = row0 + r;
    bf16x8 v = {};
    if (gr < nrows) v = ((const bf16x8*)(A + (size_t)gr * DIM))[cb];
    *(bf16x8*)&aLDS[r][cb * 8] = v;
  }
}

// acc index j covers col = (j>>2)*64 + (j&3)*16 + m.  C/D layout (verified m89):
// col = lane&15 (+tile col), row = (lane>>4)*4 + reg.
__device__ __forceinline__ void mfma_half(const __bf16 (*aLDS)[136],
    const __bf16 (*wLDS)[136], int half, f32x4 acc[8])
{
  const int lane = threadIdx.x & 63, wave = threadIdx.x >> 6;
  const int m = lane & 15, q = lane >> 4;
  #pragma unroll
  for (int kt = 0; kt < 4; ++kt) {
    bf16x8 a = *(const bf16x8*)&aLDS[wave * 16 + m][kt * 32 + q * 8];
    #pragma unroll
    for (int ct = 0; ct < 4; ++ct) {
      bf16x8 b = *(const bf16x8*)&wLDS[ct * 16 + m][kt * 32 + q * 8];
      acc[half * 4 + ct] =
          __builtin_amdgcn_mfma_f32_16x16x32_bf16(a, b, acc[half * 4 + ct], 0, 0, 0);
    }
  }
}

template <typename OutT>
__device__ __forceinline__ void store_tile(f32x4 acc[8],
    const float* __restrict__ bias, float scale, OutT* __restrict__ C,
    int row0, int nrows)
{
  const int lane = threadIdx.x & 63, wave = threadIdx.x >> 6;
  const int m = lane & 15, q = lane >> 4;
  #pragma unroll
  for (int j = 0; j < 8; ++j) {
    int col = (j >> 2) * 64 + (j & 3) * 16 + m;
    float bv = bias[col];
    #pragma unroll
    for (int r = 0; r < 4; ++r) {
      int row = row0 + wave * 16 + q * 4 + r;
      if (row < nrows) C[(size_t)row * DIM + col] = (OutT)((acc[j][r] + bv) * scale);
    }
  }
}

// one full 128-col GEMM pass over the staged A tile (two W halves)
__device__ __forceinline__ void gemm_pass(const __bf16 (*aLDS)[136],
    __bf16 (*wLDS)[136], const __bf16* __restrict__ Wt, f32x4 acc[8])
{
  #pragma unroll
  for (int i = 0; i < 8; ++i) acc[i] = (f32x4){0.f, 0.f, 0.f, 0.f};
  stage_Wt_half(Wt, 0, wLDS);
  __syncthreads();
  mfma_half(aLDS, wLDS, 0, acc);
  __syncthreads();
  stage_Wt_half(Wt, 1, wLDS);
  __syncthreads();
  mfma_half(aLDS, wLDS, 1, acc);
}

// ---------------- fat1: edge histogram || {K,M,Q} gemm (mat-split) ----------------
// R13: the K/M/Q GEMMs are latency-bound — 3 independent block sets (3x overlap),
// mat-minor ordering so the 3 readers of an x row dispatch adjacently (L3 share).
// Hist half: per-block LDS histograms over 392 buckets, zero global atomics (R11).
__global__ __launch_bounds__(256) void fat1(const int* __restrict__ ei,
    int* __restrict__ hist,
    const __bf16* __restrict__ Wt, const float* __restrict__ x,
    const float* __restrict__ bk, const float* __restrict__ bm,
    const float* __restrict__ bq,
    __bf16* __restrict__ Kn, __bf16* __restrict__ Mn, __bf16* __restrict__ Qn)
{
  __shared__ __bf16 aLDS[64][136];
  __shared__ __bf16 wLDS[64][136];
  const int b = blockIdx.x, t = threadIdx.x;

  if (b < HBLOCKS) {
    int* h = (int*)&aLDS[0][0];        // 392 ints in a corner of aLDS
    for (int i = t; i < NBUCK2; i += 256) h[i] = 0;
    __syncthreads();
    #pragma unroll
    for (int i = 0; i < 10; ++i) {
      int e = b * EPB + i * 256 + t;
      if (e < N_EDGES) {
        int s = ei[e], d = ei[N_EDGES + e];
        atomicAdd(&h[s >> 8], 1);
        atomicAdd(&h[NBUCK + (d >> 8)], 1);
      }
    }
    __syncthreads();
    for (int i = t; i < NBUCK2; i += 256) hist[b * NBUCK2 + i] = h[i];
  } else {
    const int gb = b - HBLOCKS;
    const int mat = gb % 3;            // mat-minor: 3 mats of one row adjacent
    const int row0 = (gb / 3) * 64;
    const float* bias = (mat == 0) ? bk : (mat == 1) ? bm : bq;
    __bf16* out = (mat == 0) ? Kn : (mat == 1) ? Mn : Qn;
    const float scale = (mat == 2) ? 0.17677669529663689f : 1.0f;
    f32x4 acc[8];
    stage_A_f32(x, row0, N_NODES, aLDS);
    gemm_pass(aLDS, wLDS, Wt + (size_t)mat * 16384, acc);
    store_tile<__bf16>(acc, bias, scale, out, row0, N_NODES);
  }
}

// ---------------- per-bucket scan over blocks: bbase[blk][b], tot[b] ----------------
__global__ __launch_bounds__(64) void bucket_scan(const int* __restrict__ hist,
    int* __restrict__ bbase, int* __restrict__ tot)
{
  const int b = blockIdx.x, l = threadIdx.x;   // one wave per bucket
  int run = 0;
  for (int c = 0; c < 5; ++c) {                // ceil(313/64)
    int idx = c * 64 + l;
    int v = (idx < HBLOCKS) ? hist[idx * NBUCK2 + b] : 0;
    int orig = v;
    #pragma unroll
    for (int o = 1; o < 64; o <<= 1) {
      int n = __shfl_up(v, o);
      if (l >= o) v += n;
    }
    if (idx < HBLOCKS) bbase[idx * NBUCK2 + b] = run + v - orig;  // exclusive
    run += __shfl(v, 63);
  }
  if (l == 0) tot[b] = run;
}

// ---------------- exclusive scan of bucket totals (src and dst separately) ----------------
__global__ __launch_bounds__(256) void bucket_starts(const int* __restrict__ tot,
    int* __restrict__ bstart)
{
  __shared__ int s[256];
  const int t = threadIdx.x;
  int v = (t < NBUCK) ? tot[t] : 0;
  s[t] = v; __syncthreads();
  for (int o = 1; o < 256; o <<= 1) {
    int x = (t >= o) ? s[t - o] : 0; __syncthreads();
    s[t] += x; __syncthreads();
  }
  if (t < NBUCK) bstart[t] = s[t] - v;
  __syncthreads();
  v = (t < NBUCK) ? tot[NBUCK + t] : 0;
  s[t] = v; __syncthreads();
  for (int o = 1; o < 256; o <<= 1) {
    int x = (t >= o) ? s[t - o] : 0; __syncthreads();
    s[t] += x; __syncthreads();
  }
  if (t < NBUCK) bstart[NBUCK + t] = s[t] - v;
}

// ---------------- scatter edges into per-bucket segments ----------------
// R14: slotD (the edge's dst-bucket slot) is known AT SCATTER TIME — carried in
// bucketedS's payload; wexp is indexed by slotD so the two rank sides are
// independent. bucketedD carries only pk (4B), its index IS slotD.
__global__ __launch_bounds__(256) void edge_scatter(const int* __restrict__ ei,
    const int* __restrict__ bbase, const int* __restrict__ bstart,
    int2* __restrict__ bucketedS, int* __restrict__ bucketedD)
{
  __shared__ int base[NBUCK2];
  __shared__ int cur[NBUCK2];
  const int b = blockIdx.x, t = threadIdx.x;
  for (int i = t; i < NBUCK2; i += 256) {
    base[i] = bstart[i] + bbase[b * NBUCK2 + i];
    cur[i] = 0;
  }
  __syncthreads();
  #pragma unroll
  for (int i = 0; i < 10; ++i) {
    int e = b * EPB + i * 256 + t;
    if (e < N_EDGES) {
      int s = ei[e], d = ei[N_EDGES + e];
      int pk = s | (d << 16);
      int bs = s >> 8, bd = NBUCK + (d >> 8);
      int lo = atomicAdd(&cur[bs], 1);
      int ld = atomicAdd(&cur[bd], 1);
      int slotD = base[bd] + ld;             // global dst-side slot in [0,E)
      bucketedS[base[bs] + lo] = make_int2(pk, slotD);
      bucketedD[slotD] = pk;
    }
  }
}

// ---------------- per-bucket rank + CSR emit (both sides, one dispatch) ----------------
// b<196: src bucket -> elistS=(dst, slotD), starts/deg.
// b>=196: dst bucket -> elistD = src | (bucketLocalSlot<<16), startsD/degD.
// bucketLocalSlot < ~4600 and src < 50000 both fit 16 bits.
__global__ __launch_bounds__(256) void bucket_rank(const int2* __restrict__ bucketedS,
    const int* __restrict__ bucketedD, const int* __restrict__ bstart,
    const int* __restrict__ tot,
    int2* __restrict__ elistS, int* __restrict__ elistD,
    int* __restrict__ starts, int* __restrict__ deg,
    int* __restrict__ startsD, int* __restrict__ degD)
{
  __shared__ int c1[256], ns[256], c2[256];
  const int b = blockIdx.x, t = threadIdx.x;
  const bool srcSide = (b < NBUCK);
  const int bb = srcSide ? b : b - NBUCK;
  const int seg0 = bstart[b];
  const int cnt = tot[b];

  c1[t] = 0; c2[t] = 0;
  __syncthreads();
  if (srcSide) {
    const int2* ent = bucketedS + seg0;
    for (int i = t; i < cnt; i += 256)
      atomicAdd(&c1[(int)((unsigned)ent[i].x & 0xFFFFu) - (bb << 8)], 1);
  } else {
    const int* ent = bucketedD + seg0;
    for (int i = t; i < cnt; i += 256)
      atomicAdd(&c1[(int)((unsigned)ent[i] >> 16) - (bb << 8)], 1);
  }
  __syncthreads();
  ns[t] = c1[t]; __syncthreads();
  for (int o = 1; o < 256; o <<= 1) {
    int x = (t >= o) ? ns[t - o] : 0; __syncthreads();
    ns[t] += x; __syncthreads();
  }
  {
    int node = (bb << 8) + t;
    int st = seg0 + ns[t] - c1[t];
    if (srcSide) { starts[node] = st; deg[node] = c1[t]; }
    else         { startsD[node] = st; degD[node] = c1[t]; }
  }
  __syncthreads();
  ns[t] -= c1[t];
  __syncthreads();
  if (srcSide) {
    const int2* ent = bucketedS + seg0;
    for (int i = t; i < cnt; i += 256) {
      int2 en = ent[i];
      unsigned pk = (unsigned)en.x;
      int ln = (int)(pk & 0xFFFFu) - (bb << 8);
      int r = atomicAdd(&c2[ln], 1);
      elistS[seg0 + ns[ln] + r] = make_int2((int)(pk >> 16), en.y);
    }
  } else {
    const int* ent = bucketedD + seg0;
    for (int i = t; i < cnt; i += 256) {
      unsigned pk = (unsigned)ent[i];
      int ln = (int)(pk >> 16) - (bb << 8);
      int r = atomicAdd(&c2[ln], 1);
      elistD[seg0 + ns[ln] + r] = (int)(pk & 0xFFFFu) | (i << 16);
    }
  }
}

// ---------------- pass 1: scores+exp, one wave per SRC node ----------------
// 16 edges per wave-iteration (4 groups x 4 unroll), 16 lanes/edge, bf16x8 loads.
// wexp stores RAW exp at the edge's dst-side slot (slotD from elistS payload);
// per-src factor deg/ssum stored to factor[n][h]. No max-shift: |score| < ~1.
__global__ __launch_bounds__(256) void src_scores(const int* __restrict__ starts,
    const int* __restrict__ degS, const int2* __restrict__ elistS,
    const __bf16* __restrict__ Qn, const __bf16* __restrict__ Kn,
    float* __restrict__ wexp, float* __restrict__ factor)
{
  const int wave = threadIdx.x >> 6, l = threadIdx.x & 63;
  const int n = blockIdx.x * 4 + wave;
  const int g = l >> 4, il = l & 15;
  const int h = il >> 2;
  const int beg = starts[n], end = beg + degS[n];
  if (beg == end) return;   // factor never read for edge-less src

  bf16x8 q8 = ((const bf16x8*)(Qn + (size_t)n * DIM))[il];
  float wsum = 0.f;

  for (int p0 = beg; p0 < end; p0 += 16) {
    int pp[4]; int2 en[4];
    #pragma unroll
    for (int u = 0; u < 4; ++u) {
      pp[u] = p0 + u * 4 + g;
      en[u] = elistS[min(pp[u], end - 1)];
    }
    bf16x8 kk[4];
    #pragma unroll
    for (int u = 0; u < 4; ++u)
      kk[u] = ((const bf16x8*)(Kn + (size_t)en[u].x * DIM))[il];
    #pragma unroll
    for (int u = 0; u < 4; ++u) {
      float pr = 0.f;
      #pragma unroll
      for (int j = 0; j < 8; ++j) pr += (float)q8[j] * (float)kk[u][j];
      pr += __shfl_xor(pr, 1);
      pr += __shfl_xor(pr, 2);
      float w = (pp[u] < end) ? __expf(pr) : 0.f;
      wsum += w;
      if ((pp[u] < end) && (il & 3) == 0) wexp[(size_t)en[u].y * NHEAD + h] = w;
    }
  }
  wsum += __shfl_xor(wsum, 16);
  wsum += __shfl_xor(wsum, 32);
  if (g == 0 && (il & 3) == 0)
    factor[(size_t)n * NHEAD + h] = (float)(end - beg) / wsum;
}

// ---------------- pass 2: agg[dst] = sum wexp * factor[src] * M[src], one wave/node ----
// R16: aggregation is latency-bound — wave count is the resource (12500 blocks,
// 50K waves; the 782-block fusion (R5, 77µs) and the 392-block LDS version
// (R6, 697µs) both starved it). elistD 4B (src|localSlot<<16); wexp via
// seg0d+localSlot (bucket-windowed, L2-hot); factor L2-resident; Mn random.
__global__ __launch_bounds__(256) void dst_aggregate(const int* __restrict__ startsD,
    const int* __restrict__ degD, const int* __restrict__ elistD,
    const int* __restrict__ bstart,
    const __bf16* __restrict__ Mn, const float* __restrict__ wexp,
    const float* __restrict__ factor, __bf16* __restrict__ agg)
{
  const int wave = threadIdx.x >> 6, l = threadIdx.x & 63;
  const int n = blockIdx.x * 4 + wave;
  const int g = l >> 4, il = l & 15;
  const int h = il >> 2;
  const int beg = startsD[n], end = beg + degD[n];
  const int seg0d = bstart[NBUCK + (n >> 8)];

  float acc[8];
  #pragma unroll
  for (int j = 0; j < 8; ++j) acc[j] = 0.f;

  for (int q0 = beg; q0 < end; q0 += 16) {
    int qq[4], ss[4]; float ww[4];
    #pragma unroll
    for (int u = 0; u < 4; ++u) {
      qq[u] = q0 + u * 4 + g;
      int cq = min(qq[u], end - 1);
      int v = elistD[cq];
      ss[u] = v & 0xFFFF;
      ww[u] = wexp[(size_t)(seg0d + ((unsigned)v >> 16)) * NHEAD + h];
    }
    float ff[4];
    #pragma unroll
    for (int u = 0; u < 4; ++u) ff[u] = factor[(size_t)ss[u] * NHEAD + h];
    bf16x8 mm[4];
    #pragma unroll
    for (int u = 0; u < 4; ++u)
      mm[u] = ((const bf16x8*)(Mn + (size_t)ss[u] * DIM))[il];
    #pragma unroll
    for (int u = 0; u < 4; ++u) {
      float av = (qq[u] < end) ? ww[u] * ff[u] : 0.f;
      #pragma unroll
      for (int j = 0; j < 8; ++j) acc[j] += (float)mm[u][j] * av;
    }
  }
  #pragma unroll
  for (int j = 0; j < 8; ++j) {
    acc[j] += __shfl_xor(acc[j], 16);
    acc[j] += __shfl_xor(acc[j], 32);
  }
  if (g == 0) {
    bf16x8 o;
    #pragma unroll
    for (int j = 0; j < 8; ++j) o[j] = (__bf16)acc[j];
    *(bf16x8*)(agg + (size_t)n * DIM + il * 8) = o;
  }
}

// ---------------- gemm1: h1 = agg@W1+b1 (bf16 out) + fused column stats ----------------
__global__ __launch_bounds__(256) void gemm_stats(const __bf16* __restrict__ A,
    const __bf16* __restrict__ Wt, const float* __restrict__ bias,
    __bf16* __restrict__ C, float* __restrict__ colsum, float* __restrict__ colsq)
{
  __shared__ __bf16 aLDS[64][136];
  __shared__ __bf16 wLDS[64][136];
  __shared__ float csum[128], csq[128];
  const int t = threadIdx.x;
  const int row0 = blockIdx.x * 64;

  stage_A_bf16(A, row0, N_NODES, aLDS);
  if (t < 128) { csum[t] = 0.f; csq[t] = 0.f; }
  f32x4 acc[8];
  gemm_pass(aLDS, wLDS, Wt, acc);

  const int lane = t & 63, wave = t >> 6;
  const int m = lane & 15, q = lane >> 4;
  #pragma unroll
  for (int j = 0; j < 8; ++j) {
    int col = (j >> 2) * 64 + (j & 3) * 16 + m;
    float bv = bias[col];
    float s = 0.f, s2 = 0.f;
    #pragma unroll
    for (int r = 0; r < 4; ++r) {
      int row = row0 + wave * 16 + q * 4 + r;
      float hv = acc[j][r] + bv;
      if (row < N_NODES) {
        C[(size_t)row * DIM + col] = (__bf16)hv;
        s += hv; s2 += hv * hv;
      }
    }
    s  += __shfl_xor(s, 16);  s  += __shfl_xor(s, 32);
    s2 += __shfl_xor(s2, 16); s2 += __shfl_xor(s2, 32);
    if (q == 0) {
      atomicAdd(&csum[col], s);
      atomicAdd(&csq[col], s2);
    }
  }
  __syncthreads();
  if (t < 128) {
    atomicAdd(&colsum[t], csum[t]);
    atomicAdd(&colsq[t], csq[t]);
  }
}

// ---------------- gemm2: out = relu(BN(h1))@W2+b2, BN folded in ----------------
__global__ __launch_bounds__(256) void gemm_bn(const __bf16* __restrict__ A,
    const __bf16* __restrict__ Wt, const float* __restrict__ bias,
    float* __restrict__ C, const float* __restrict__ colsum,
    const float* __restrict__ colsq, const float* __restrict__ gamma,
    const float* __restrict__ beta)
{
  __shared__ __bf16 aLDS[64][136];
  __shared__ __bf16 wLDS[64][136];
  __shared__ float sA[128], sB[128];
  const int t = threadIdx.x;
  const int row0 = blockIdx.x * 64;

  if (t < 128) {
    float mean = colsum[t] * (1.0f / N_NODES);
    float var = colsq[t] * (1.0f / N_NODES) - mean * mean;  // biased (torch BN)
    float inv = rsqrtf(var + 1e-5f);
    float a = gamma[t] * inv;
    sA[t] = a;
    sB[t] = beta[t] - mean * a;
  }
  __syncthreads();

  {
    const int cb = t & 15;
    float sa[8], sb[8];
    #pragma unroll
    for (int j = 0; j < 8; ++j) { sa[j] = sA[cb * 8 + j]; sb[j] = sB[cb * 8 + j]; }
    #pragma unroll
    for (int i = 0; i < 4; ++i) {
      int id = t + i * 256;
      int r = id >> 4;
      int gr = row0 + r;
      bf16x8 v = {};
      if (gr < N_NODES) v = ((const bf16x8*)(A + (size_t)gr * DIM))[cb];
      bf16x8 o;
      #pragma unroll
      for (int j = 0; j < 8; ++j)
        o[j] = (__bf16)fmaxf((float)v[j] * sa[j] + sb[j], 0.f);
      *(bf16x8*)&aLDS[r][cb * 8] = o;
    }
  }
  f32x4 acc[8];
  gemm_pass(aLDS, wLDS, Wt, acc);
  store_tile<float>(acc, bias, 1.0f, C, row0, N_NODES);
}

extern "C" void kernel_launch(void* const* d_in, const int* in_sizes, int n_in,
                              void* d_out, int out_size, void* d_ws, size_t ws_size,
                              hipStream_t stream) {
  const float* x     = (const float*)d_in[0];
  const int*   ei    = (const int*)d_in[1];
  const float* Wk    = (const float*)d_in[2];
  const float* bk    = (const float*)d_in[3];
  const float* Wm    = (const float*)d_in[4];
  const float* bm    = (const float*)d_in[5];
  const float* Wq    = (const float*)d_in[6];
  const float* bq    = (const float*)d_in[7];
  const float* W1    = (const float*)d_in[8];
  const float* b1    = (const float*)d_in[9];
  const float* gamma = (const float*)d_in[10];
  const float* beta  = (const float*)d_in[11];
  const float* W2    = (const float*)d_in[12];
  const float* b2    = (const float*)d_in[13];

  float* ws = (float*)d_ws;
  const size_t ND  = (size_t)N_NODES * DIM;      // 6,400,000
  const size_t NDh = ND / 2;                     // floats per bf16 ND array
  const size_t EH  = (size_t)N_EDGES * NHEAD;    // 3,200,000

  __bf16* Kn   = (__bf16*)ws;                    // ND bf16
  __bf16* Mn   = (__bf16*)(ws + NDh);            // ND bf16 (unscaled)
  __bf16* Qn   = (__bf16*)(ws + 2 * NDh);        // ND bf16
  __bf16* agg  = (__bf16*)(ws + 3 * NDh);        // ND bf16
  __bf16* h1   = (__bf16*)(ws + 4 * NDh);        // ND bf16
  float*  wexp = ws + 5 * NDh;                   // EH fp32 (raw exp, by slotD)
  // bucketed arrays alias wexp: dead before src_scores writes wexp
  int2*   bucketedS = (int2*)wexp;               // E int2 (pk, slotD)  6.4MB
  int*    bucketedD = (int*)(bucketedS + N_EDGES); // E int (pk)  +3.2MB <= 12.8MB
  int2*   elistS = (int2*)(wexp + EH);           // E int2 (dst, slotD)
  int*    elistD = (int*)(elistS + N_EDGES);     // E int  (src | localSlot<<16)
  int*    hist   = elistD + N_EDGES;             // HBLOCKS * 392
  int*    bbase  = hist + HBLOCKS * NBUCK2;      // HBLOCKS * 392
  int*    tot    = bbase + HBLOCKS * NBUCK2;     // 392
  int*    bstart = tot + NBUCK2;                 // 392
  int*    starts = bstart + NBUCK2;              // NODE_PAD
  int*    deg    = starts + NODE_PAD;            // NODE_PAD
  int*    startsD= deg + NODE_PAD;               // NODE_PAD
  int*    degD   = startsD + NODE_PAD;           // NODE_PAD
  float*  factor = (float*)(degD + NODE_PAD);    // NHEAD * N
  float*  colsum = factor + (size_t)NHEAD * N_NODES;  // 128
  float*  colsq  = colsum + 128;                 // 128
  __bf16* Wt     = (__bf16*)(colsq + 128);       // 5*16384 bf16
  float*  outp   = (float*)d_out;

  // zero: colsum/colsq only (everything else fully written by kernels)
  hipMemsetAsync(colsum, 0, 256 * sizeof(float), stream);

  const int node_blocks = N_NODES / 4;           // 12500

  WPtrs wp; wp.w[0] = Wk; wp.w[1] = Wm; wp.w[2] = Wq; wp.w[3] = W1; wp.w[4] = W2;
  prep_weights<<<40, 256, 0, stream>>>(wp, Wt);

  fat1<<<HBLOCKS + 3 * GEMM_BLOCKS, 256, 0, stream>>>(
      ei, hist, Wt, x, bk, bm, bq, Kn, Mn, Qn);

  bucket_scan<<<NBUCK2, 64, 0, stream>>>(hist, bbase, tot);
  bucket_starts<<<1, 256, 0, stream>>>(tot, bstart);
  edge_scatter<<<HBLOCKS, 256, 0, stream>>>(ei, bbase, bstart, bucketedS, bucketedD);
  bucket_rank<<<NBUCK2, 256, 0, stream>>>(bucketedS, bucketedD, bstart, tot,
                                          elistS, elistD, starts, deg,
                                          startsD, degD);

  src_scores<<<node_blocks, 256, 0, stream>>>(starts, deg, elistS, Qn, Kn,
                                              wexp, factor);
  dst_aggregate<<<node_blocks, 256, 0, stream>>>(startsD, degD, elistD, bstart,
                                                 Mn, wexp, factor, agg);

  gemm_stats<<<GEMM_BLOCKS, 256, 0, stream>>>(agg, Wt + 3 * 16384, b1, h1,
                                              colsum, colsq);
  gemm_bn<<<GEMM_BLOCKS, 256, 0, stream>>>(h1, Wt + 4 * 16384, b2, outp,
                                           colsum, colsq, gamma, beta);
}